// Round 6
// baseline (220.052 us; speedup 1.0000x reference)
//
#include <hip/hip_runtime.h>
#include <hip/hip_bf16.h>
#include <math.h>

// Problem constants (B=2, I=8, J=1025, M=256, H=8, Dh=32)
#define BB   2
#define II   8
#define JJ   1025
#define MM   256
#define HH   8
#define DH   32
#define BI   (BB*II)          // 16
#define RTOT (BI*JJ)          // 16400 rows (tokens)
#define NQKV (3*MM)           // 768
#define HID  (4*MM)           // 1024
#define MPAD 16512            // 258*64 (rows padded to 64-tile multiple)

// GEMM tile: 64 x 128 x 32, 256 threads = 4 waves
#define BM 64
#define BN 128
#define BK 32
#define LP 40   // LDS pitch bf16 (80 B): 2-way bank alias = free, 16B aligned

#define WQN (NQKV*MM)         // 196608
#define W1N (HID*MM)          // 262144
#define W2N (MM*HID)          // 262144

typedef unsigned short ushort;
typedef __attribute__((ext_vector_type(8))) short short8;    // 8 bf16
typedef __attribute__((ext_vector_type(4))) float f32x4;
typedef __attribute__((ext_vector_type(4))) ushort ushort4v; // 4 bf16 (8 B)

__device__ __forceinline__ ushort f2bf(float x) {
    __hip_bfloat16 h = __float2bfloat16(x);
    return *reinterpret_cast<ushort*>(&h);
}
__device__ __forceinline__ float bf2f(ushort u) {
    __hip_bfloat16 h = *reinterpret_cast<__hip_bfloat16*>(&u);
    return __bfloat162float(h);
}
__device__ __forceinline__ float gelu_exact(float x) {
    return 0.5f * x * (1.0f + erff(x * 0.70710678118654752f));
}
__device__ __forceinline__ float wave_sum(float v) {
#pragma unroll
    for (int off = 32; off > 0; off >>= 1) v += __shfl_xor(v, off);
    return v;
}
__device__ __forceinline__ float block_sum256(float v, float* red, int t) {
    red[t] = v; __syncthreads();
    for (int s = 128; s > 0; s >>= 1) {
        if (t < s) red[t] += red[t + s];
        __syncthreads();
    }
    float r = red[0]; __syncthreads();
    return r;
}

// ---------------------------------------------------------------------------
// K_prep: weight casts + Wo row-sums + KtV zero + Hbf pad zero + LN1 (fused)
// ---------------------------------------------------------------------------
__global__ __launch_bounds__(256) void k_prep(
    const float* __restrict__ wq, const float* __restrict__ w1,
    const float* __restrict__ w2, const float* __restrict__ Wo,
    const float* __restrict__ save, const float* __restrict__ g1,
    const float* __restrict__ b1,
    ushort* __restrict__ dq, ushort* __restrict__ d1, ushort* __restrict__ d2,
    float* __restrict__ woSum, float* __restrict__ KtV,
    ushort* __restrict__ Hbf, ushort* __restrict__ Ah)
{
    __shared__ float red[256];
    const int gb = blockIdx.x, t = threadIdx.x;
    if (gb < 2816) {
        int i = gb * 256 + t;
        if (i < WQN) dq[i] = f2bf(wq[i]);
        else if (i < WQN + W1N) d1[i - WQN] = f2bf(w1[i - WQN]);
        else d2[i - WQN - W1N] = f2bf(w2[i - WQN - W1N]);
    } else if (gb < 3072) {
        int m = gb - 2816;
        float s = block_sum256(Wo[m * MM + t], red, t);
        if (t == 0) woSum[m] = s;
    } else if (gb < 3584) {
        KtV[(gb - 3072) * 256 + t] = 0.0f;
    } else if (gb < 3696) {
        int row = RTOT + (gb - 3584);
        Hbf[(size_t)row * MM + t] = 0;
    } else {
        // LN1 + bf16 cast, wave per row
        const int wave = t >> 6, l = t & 63;
        const int row = (gb - 3696) * 4 + wave;
        const size_t base = (size_t)row * MM + 4 * l;
        if (row >= RTOT) { ushort4v z = 0; *(ushort4v*)&Ah[base] = z; return; }
        f32x4 v = *(const f32x4*)&save[base];
        float mu = wave_sum(v[0] + v[1] + v[2] + v[3]) * (1.0f / MM);
        f32x4 d;
#pragma unroll
        for (int c = 0; c < 4; ++c) d[c] = v[c] - mu;
        float var = wave_sum(d[0]*d[0] + d[1]*d[1] + d[2]*d[2] + d[3]*d[3]) * (1.0f / MM);
        float rstd = 1.0f / sqrtf(var + 1e-5f);
        f32x4 g = *(const f32x4*)&g1[4 * l];
        f32x4 b = *(const f32x4*)&b1[4 * l];
        ushort4v o;
#pragma unroll
        for (int c = 0; c < 4; ++c) o[c] = f2bf(d[c] * rstd * g[c] + b[c]);
        *(ushort4v*)&Ah[base] = o;
    }
}

// ---------------------------------------------------------------------------
// MFMA GEMM template: C[r][n] = epi( sum_k A[r][k] * W[n][k] ), bf16 in,
// 64x128x32, double-buffered LDS + register prefetch, 1 barrier/k-iter.
// Used for QKV (K=256), FC1 (K=256, gelu->bf16), FC2 (K=1024, +b+s2->fp32).
// ---------------------------------------------------------------------------
template <bool GELU_EPI, bool ADD_EPI, bool STORE_BF16, bool GUARD_M>
__global__ __launch_bounds__(256, 4) void k_gemm(
    const ushort* __restrict__ A, const ushort* __restrict__ W,
    const float* __restrict__ bias,      // [N] or nullptr
    const float* __restrict__ addsrc,    // [Mrows][ldc] or nullptr
    void* __restrict__ Cout, int ldc,
    int K, int Mrows)
{
    __shared__ __align__(16) ushort sA[2][BM * LP];
    __shared__ __align__(16) ushort sB[2][BN * LP];

    const int tid  = threadIdx.x;
    const int wave = tid >> 6;
    const int lane = tid & 63;
    const int lrow = lane & 15;
    const int quad = lane >> 4;
    const int row0 = blockIdx.y * BM;
    const int col0 = blockIdx.x * BN;
    const int ar = tid >> 2;
    const int ac = (tid & 3) * 8;
    const int KT = K / BK;

    f32x4 acc[4][2] = {};

    f32x4 ra, rb0, rb1;
    ra  = *(const f32x4*)(A + (size_t)(row0 + ar) * K + ac);
    rb0 = *(const f32x4*)(W + (size_t)(col0 + ar) * K + ac);
    rb1 = *(const f32x4*)(W + (size_t)(col0 + ar + 64) * K + ac);
    *(f32x4*)&sA[0][ar * LP + ac] = ra;
    *(f32x4*)&sB[0][ar * LP + ac] = rb0;
    *(f32x4*)&sB[0][(ar + 64) * LP + ac] = rb1;

    for (int kt = 0; kt < KT; ++kt) {
        __syncthreads();
        const int cur = kt & 1, nxt = cur ^ 1;
        const bool more = (kt + 1 < KT);
        if (more) {
            const int kk = (kt + 1) * BK;
            ra  = *(const f32x4*)(A + (size_t)(row0 + ar) * K + kk + ac);
            rb0 = *(const f32x4*)(W + (size_t)(col0 + ar) * K + kk + ac);
            rb1 = *(const f32x4*)(W + (size_t)(col0 + ar + 64) * K + kk + ac);
        }
        short8 fa[4], fb[2];
#pragma unroll
        for (int i = 0; i < 4; ++i)
            fa[i] = *(const short8*)&sA[cur][(i * 16 + lrow) * LP + quad * 8];
#pragma unroll
        for (int j = 0; j < 2; ++j)
            fb[j] = *(const short8*)&sB[cur][(wave * 32 + j * 16 + lrow) * LP + quad * 8];
#pragma unroll
        for (int i = 0; i < 4; ++i)
#pragma unroll
            for (int j = 0; j < 2; ++j)
                acc[i][j] = __builtin_amdgcn_mfma_f32_16x16x32_bf16(
                    fa[i], fb[j], acc[i][j], 0, 0, 0);
        if (more) {
            *(f32x4*)&sA[nxt][ar * LP + ac] = ra;
            *(f32x4*)&sB[nxt][ar * LP + ac] = rb0;
            *(f32x4*)&sB[nxt][(ar + 64) * LP + ac] = rb1;
        }
    }

    // epilogue: C/D layout col=lane&15, row=quad*4+reg
#pragma unroll
    for (int i = 0; i < 4; ++i)
#pragma unroll
        for (int j = 0; j < 2; ++j) {
            const int ncol = col0 + wave * 32 + j * 16 + lrow;
            const float bv = bias ? bias[ncol] : 0.0f;
#pragma unroll
            for (int v = 0; v < 4; ++v) {
                const int r = row0 + i * 16 + quad * 4 + v;
                if (GUARD_M && r >= Mrows) continue;
                float c = acc[i][j][v] + bv;
                if (GELU_EPI) c = gelu_exact(c);
                if (ADD_EPI) c += addsrc[(size_t)r * ldc + ncol];
                if (STORE_BF16) ((ushort*)Cout)[(size_t)r * ldc + ncol] = f2bf(c);
                else            ((float*)Cout)[(size_t)r * ldc + ncol] = c;
            }
        }
}

// ---------------------------------------------------------------------------
// K_ktv: split-J partial KtV, scale folded, atomicAdd into zeroed KtV.
// grid (BI*H, 8).
// ---------------------------------------------------------------------------
__global__ __launch_bounds__(256) void k_ktv(const ushort* __restrict__ qkv,
                                             float* __restrict__ KtV) {
    __shared__ float Ks[8][32];
    __shared__ float Vs[8][32];

    const int bih = blockIdx.x;
    const int sp  = blockIdx.y;
    const int bi = bih >> 3;
    const int h  = bih & 7;
    const ushort* baseK = qkv + (size_t)bi * JJ * NQKV + MM     + h * DH;
    const ushort* baseV = qkv + (size_t)bi * JJ * NQKV + 2 * MM + h * DH;

    const int jbeg = sp * 129;
    const int jend = min(JJ, jbeg + 129);

    const int t = threadIdx.x;
    const int srow = t >> 5;
    const int scol = t & 31;
    const int d2 = t & 31;
    const int d1b = t >> 5;

    float acc[4] = {0.f, 0.f, 0.f, 0.f};

    for (int jb = jbeg; jb < jend; jb += 8) {
        int j = jb + srow;
        float kv = 0.f, vv = 0.f;
        if (j < jend) {
            kv = bf2f(baseK[(size_t)j * NQKV + scol]);
            vv = bf2f(baseV[(size_t)j * NQKV + scol]);
        }
        Ks[srow][scol] = kv;
        Vs[srow][scol] = vv;
        __syncthreads();
#pragma unroll
        for (int jl = 0; jl < 8; ++jl) {
            float v = Vs[jl][d2];
#pragma unroll
            for (int p = 0; p < 4; ++p) acc[p] += Ks[jl][d1b + 8 * p] * v;
        }
        __syncthreads();
    }

    const float scale = 0.17677669529663687f;  // 1/sqrt(32)
    float* out = KtV + (size_t)bih * 1024;
#pragma unroll
    for (int p = 0; p < 4; ++p)
        atomicAdd(&out[(d1b + 8 * p) * DH + d2], scale * acc[p]);
}

// ---------------------------------------------------------------------------
// K_imv: s2 = woSum*(Q@KtV) + save; fused LN2 -> Hbf. Wave handles 4 rows.
// grid (65 jchunks, 16 bi).
// ---------------------------------------------------------------------------
__global__ __launch_bounds__(256) void k_imv_s2(const ushort* __restrict__ qkv,
                                                const float* __restrict__ KtV,
                                                const float* __restrict__ woSum,
                                                const float* __restrict__ save,
                                                const float* __restrict__ g2,
                                                const float* __restrict__ b2,
                                                float* __restrict__ s2,
                                                ushort* __restrict__ Hbf) {
    const int tid = threadIdx.x, wave = tid >> 6, l = tid & 63;
    const int jc = blockIdx.x, bi = blockIdx.y;
    const int jbase = jc * 16 + wave * 4;

    float qv[4][4];
#pragma unroll
    for (int rr = 0; rr < 4; ++rr) {
        int j = jbase + rr;
        if (j < JJ) {
            ushort4v q = *(const ushort4v*)&qkv[((size_t)(bi * JJ + j)) * NQKV + 4 * l];
#pragma unroll
            for (int c = 0; c < 4; ++c) qv[rr][c] = bf2f(q[c]);
        } else {
#pragma unroll
            for (int c = 0; c < 4; ++c) qv[rr][c] = 0.f;
        }
    }

    const float* kvb = KtV + (size_t)bi * 8192 + (l >> 3) * 1024 + (l & 7) * 4;
    float acc[4][4] = {};
#pragma unroll
    for (int dd = 0; dd < 32; ++dd) {
        f32x4 kvv = *(const f32x4*)&kvb[dd * 32];
        const int src = (l & 56) + (dd >> 2);
#pragma unroll
        for (int rr = 0; rr < 4; ++rr) {
            float qq = __shfl(qv[rr][dd & 3], src);
#pragma unroll
            for (int c = 0; c < 4; ++c) acc[rr][c] += qq * kvv[c];
        }
    }

    f32x4 ws = *(const f32x4*)&woSum[4 * l];
    f32x4 g  = *(const f32x4*)&g2[4 * l];
    f32x4 b  = *(const f32x4*)&b2[4 * l];

#pragma unroll
    for (int rr = 0; rr < 4; ++rr) {
        int j = jbase + rr;
        bool valid = (j < JJ);
        size_t base = ((size_t)(bi * JJ + (valid ? j : 0))) * MM + 4 * l;
        f32x4 sv = *(const f32x4*)&save[base];
        f32x4 val;
#pragma unroll
        for (int c = 0; c < 4; ++c) val[c] = ws[c] * acc[rr][c] + sv[c];
        float mu = wave_sum(val[0] + val[1] + val[2] + val[3]) * (1.0f / MM);
        f32x4 d;
#pragma unroll
        for (int c = 0; c < 4; ++c) d[c] = val[c] - mu;
        float var = wave_sum(d[0]*d[0] + d[1]*d[1] + d[2]*d[2] + d[3]*d[3]) * (1.0f / MM);
        float rstd = 1.0f / sqrtf(var + 1e-5f);
        if (valid) {
            *(f32x4*)&s2[base] = val;
            ushort4v o;
#pragma unroll
            for (int c = 0; c < 4; ++c) o[c] = f2bf(d[c] * rstd * g[c] + b[c]);
            *(ushort4v*)&Hbf[base] = o;
        }
    }
}

// ---------------------------------------------------------------------------
extern "C" void kernel_launch(void* const* d_in, const int* in_sizes, int n_in,
                              void* d_out, int out_size, void* d_ws, size_t ws_size,
                              hipStream_t stream) {
    const float* savespace = (const float*)d_in[1];
    const float* Wqkv      = (const float*)d_in[2];   // [768][256]
    const float* Wo        = (const float*)d_in[3];
    const float* ln1_g     = (const float*)d_in[4];
    const float* ln1_b     = (const float*)d_in[5];
    const float* ln2_g     = (const float*)d_in[6];
    const float* ln2_b     = (const float*)d_in[7];
    const float* fc1_w     = (const float*)d_in[8];   // [1024][256]
    const float* fc1_b     = (const float*)d_in[9];
    const float* fc2_w     = (const float*)d_in[10];  // [256][1024]
    const float* fc2_b     = (const float*)d_in[11];
    float* out = (float*)d_out;

    // ---- workspace layout (~95 MB, no aliasing; ws is 256 MB) ----
    char* w = (char*)d_ws;
    ushort* Ah   = (ushort*)w;                                  //  8,454,144
    ushort* qkv  = (ushort*)(w + 8454144);                      // 25,362,432
    float*  s2   = (float*) (w + 8454144 + 25362432);           // 16,908,288
    ushort* Hbf  = (ushort*)(w + 8454144 + 25362432 + 16908288);//  8,454,144
    ushort* T    = (ushort*)(w + 8454144 + 25362432 + 16908288 + 8454144); // 33,816,576
    char* c4 = w + 8454144 + 25362432 + 16908288 + 8454144 + 33816576;
    ushort* WqkvB = (ushort*)c4;                                //    393,216
    ushort* F1B   = (ushort*)(c4 + WQN * 2);                    //    524,288
    ushort* F2B   = (ushort*)(c4 + WQN * 2 + W1N * 2);          //    524,288
    float*  KtV   = (float*) (c4 + WQN * 2 + W1N * 2 + W2N * 2);//    524,288
    float*  woSum = (float*) (c4 + WQN * 2 + W1N * 2 + W2N * 2 + 524288);

    // 1) prep: weight casts + wosum + KtV zero + Hbf pad zero + LN1
    k_prep<<<3696 + MPAD / 4, 256, 0, stream>>>(
        Wqkv, fc1_w, fc2_w, Wo, savespace, ln1_g, ln1_b,
        WqkvB, F1B, F2B, woSum, KtV, Hbf, Ah);
    // 2) qkv = Ah @ Wqkv^T  grid(6, 258)
    {
        dim3 grid(NQKV / BN, MPAD / BM);
        k_gemm<false, false, true, false><<<grid, 256, 0, stream>>>(
            Ah, WqkvB, nullptr, nullptr, qkv, NQKV, MM, RTOT);
    }
    // 3) KtV via atomics
    {
        dim3 grid(BI * HH, 8);
        k_ktv<<<grid, 256, 0, stream>>>(qkv, KtV);
    }
    // 4) s2 + fused LN2 -> Hbf  grid(65, 16)
    {
        dim3 grid(65, BI);
        k_imv_s2<<<grid, 256, 0, stream>>>(qkv, KtV, woSum, savespace,
                                           ln2_g, ln2_b, s2, Hbf);
    }
    // 5) T = gelu(Hbf @ F1^T + b1) -> bf16   grid(8, 258)
    {
        dim3 grid(HID / BN, MPAD / BM);
        k_gemm<true, false, true, false><<<grid, 256, 0, stream>>>(
            Hbf, F1B, fc1_b, nullptr, T, HID, MM, RTOT);
    }
    // 6) out = T @ F2^T + b2 + s2  (fp32)   grid(2, 258)
    {
        dim3 grid(MM / BN, MPAD / BM);
        k_gemm<false, true, false, true><<<grid, 256, 0, stream>>>(
            T, F2B, fc2_b, s2, out, MM, HID, RTOT);
    }
}